// Round 2
// baseline (411.417 us; speedup 1.0000x reference)
//
#include <hip/hip_runtime.h>
#include <hip/hip_bf16.h>

#define N_NODES 100000
#define N_EDGES 1250000
#define D_FEAT  64
#define SCAN_THREADS 1024
#define CHUNK ((N_NODES + SCAN_THREADS - 1) / SCAN_THREADS)   // 98

// Phase 1: rank[e] = running count of edges with same dst (int atomics, 64x fewer than fp32 scheme)
__global__ __launch_bounds__(256) void histo_rank(
    const int* __restrict__ dst, int* __restrict__ count, int* __restrict__ rank)
{
    int e = blockIdx.x * blockDim.x + threadIdx.x;
    if (e < N_EDGES) rank[e] = atomicAdd(&count[dst[e]], 1);
}

// Phase 2: exclusive prefix sum of count -> offsets (single block)
__global__ __launch_bounds__(SCAN_THREADS) void scan_offsets(
    const int* __restrict__ count, int* __restrict__ offsets)
{
    __shared__ int sums[SCAN_THREADS];
    const int t = threadIdx.x;
    const int base = t * CHUNK;

    int s = 0;
    for (int i = 0; i < CHUNK; ++i) {
        int idx = base + i;
        if (idx < N_NODES) s += count[idx];
    }
    sums[t] = s;
    __syncthreads();

    // Hillis-Steele inclusive scan in LDS
    for (int off = 1; off < SCAN_THREADS; off <<= 1) {
        int v = (t >= off) ? sums[t - off] : 0;
        __syncthreads();
        sums[t] += v;
        __syncthreads();
    }

    int run = (t == 0) ? 0 : sums[t - 1];   // exclusive prefix of this chunk
    for (int i = 0; i < CHUNK; ++i) {
        int idx = base + i;
        if (idx < N_NODES) { offsets[idx] = run; run += count[idx]; }
    }
    if (t == SCAN_THREADS - 1) offsets[N_NODES] = sums[SCAN_THREADS - 1]; // total
}

// Phase 3: counting-sort scatter of src indices by dst
__global__ __launch_bounds__(256) void scatter_src(
    const int* __restrict__ src, const int* __restrict__ dst,
    const int* __restrict__ rank, const int* __restrict__ offsets,
    int* __restrict__ sorted)
{
    int e = blockIdx.x * blockDim.x + threadIdx.x;
    if (e < N_EDGES) sorted[offsets[dst[e]] + rank[e]] = src[e];
}

// Phase 4: one wave per node, lane = feature. Pure gather + register accumulate.
__global__ __launch_bounds__(256) void gather_sum(
    const float* __restrict__ x, const int* __restrict__ sorted,
    const int* __restrict__ offsets, float* __restrict__ out)
{
    const int tid  = blockIdx.x * blockDim.x + threadIdx.x;
    const int node = tid >> 6;
    const int lane = tid & 63;
    if (node >= N_NODES) return;

    const int start = offsets[node];
    const int end   = offsets[node + 1];

    float acc0 = 0.f, acc1 = 0.f;
    int i = start;
    for (; i + 1 < end; i += 2) {          // 2-wide unroll for MLP
        int s0 = sorted[i];
        int s1 = sorted[i + 1];
        acc0 += x[(size_t)s0 * D_FEAT + lane];
        acc1 += x[(size_t)s1 * D_FEAT + lane];
    }
    if (i < end) acc0 += x[(size_t)sorted[i] * D_FEAT + lane];

    out[(size_t)node * D_FEAT + lane] = acc0 + acc1;
}

extern "C" void kernel_launch(void* const* d_in, const int* in_sizes, int n_in,
                              void* d_out, int out_size, void* d_ws, size_t ws_size,
                              hipStream_t stream) {
    const float* x = (const float*)d_in[0];
    const int* edge_index = (const int*)d_in[1];    // [2, N_EDGES] flat int32
    const int* src = edge_index;
    const int* dst = edge_index + N_EDGES;
    float* out = (float*)d_out;

    // Workspace layout (ints): count[N_NODES] | offsets[N_NODES+1] | rank[N_EDGES] | sorted[N_EDGES]
    int* count   = (int*)d_ws;
    int* offsets = count + N_NODES;
    int* rank    = offsets + (N_NODES + 1);
    int* sorted  = rank + N_EDGES;

    hipMemsetAsync(count, 0, (size_t)N_NODES * sizeof(int), stream);

    const int eb = 256;
    const int eg = (N_EDGES + eb - 1) / eb;
    histo_rank<<<eg, eb, 0, stream>>>(dst, count, rank);
    scan_offsets<<<1, SCAN_THREADS, 0, stream>>>(count, offsets);
    scatter_src<<<eg, eb, 0, stream>>>(src, dst, rank, offsets, sorted);

    const int gthreads = N_NODES * 64;
    gather_sum<<<(gthreads + 255) / 256, 256, 0, stream>>>(x, sorted, offsets, out);
}

// Round 3
// 199.819 us; speedup vs baseline: 2.0590x; 2.0590x over previous
//
#include <hip/hip_runtime.h>
#include <hip/hip_bf16.h>

#define N_NODES 100000
#define N_EDGES 1250000
#define D_FEAT  64

#define SCAN_BLOCK 256
#define N_SCAN_BLOCKS ((N_NODES + SCAN_BLOCK - 1) / SCAN_BLOCK)   // 391
#define SCAN2_THREADS 512                                          // >= N_SCAN_BLOCKS

// Phase 1: histogram + per-edge rank (1.25M int atomics)
__global__ __launch_bounds__(256) void histo_rank(
    const int* __restrict__ dst, int* __restrict__ count, int* __restrict__ rank)
{
    int e = blockIdx.x * blockDim.x + threadIdx.x;
    if (e < N_EDGES) rank[e] = atomicAdd(&count[dst[e]], 1);
}

// Phase 2a: per-block local exclusive scan; block totals out
__global__ __launch_bounds__(SCAN_BLOCK) void scan_local(
    const int* __restrict__ count, int* __restrict__ offsets,
    int* __restrict__ blockSums)
{
    __shared__ int s[SCAN_BLOCK];
    const int t = threadIdx.x;
    const int idx = blockIdx.x * SCAN_BLOCK + t;
    const int my = (idx < N_NODES) ? count[idx] : 0;
    s[t] = my;
    __syncthreads();
    for (int off = 1; off < SCAN_BLOCK; off <<= 1) {
        int v = (t >= off) ? s[t - off] : 0;
        __syncthreads();
        s[t] += v;
        __syncthreads();
    }
    if (idx < N_NODES) offsets[idx] = s[t] - my;      // local exclusive
    if (t == SCAN_BLOCK - 1) blockSums[blockIdx.x] = s[t];
}

// Phase 2b: scan the block sums (single small block), emit exclusive bases + total
__global__ __launch_bounds__(SCAN2_THREADS) void scan_blocks(
    const int* __restrict__ blockSums, int* __restrict__ blockBase,
    int* __restrict__ offsets)
{
    __shared__ int s[SCAN2_THREADS];
    const int t = threadIdx.x;
    const int my = (t < N_SCAN_BLOCKS) ? blockSums[t] : 0;
    s[t] = my;
    __syncthreads();
    for (int off = 1; off < SCAN2_THREADS; off <<= 1) {
        int v = (t >= off) ? s[t - off] : 0;
        __syncthreads();
        s[t] += v;
        __syncthreads();
    }
    if (t < N_SCAN_BLOCKS) blockBase[t] = s[t] - my;  // exclusive base
    if (t == SCAN2_THREADS - 1) offsets[N_NODES] = s[t];  // grand total == N_EDGES
}

// Phase 2c: add block bases
__global__ __launch_bounds__(SCAN_BLOCK) void scan_add_base(
    int* __restrict__ offsets, const int* __restrict__ blockBase)
{
    const int idx = blockIdx.x * SCAN_BLOCK + threadIdx.x;
    if (idx < N_NODES) offsets[idx] += blockBase[blockIdx.x];
}

// Phase 3: counting-sort scatter of src indices by dst
__global__ __launch_bounds__(256) void scatter_src(
    const int* __restrict__ src, const int* __restrict__ dst,
    const int* __restrict__ rank, const int* __restrict__ offsets,
    int* __restrict__ sorted)
{
    int e = blockIdx.x * blockDim.x + threadIdx.x;
    if (e < N_EDGES) sorted[offsets[dst[e]] + rank[e]] = src[e];
}

// Phase 4: 16 lanes x float4 per node (4 nodes per wave). Pure gather + register acc.
__global__ __launch_bounds__(256) void gather_sum4(
    const float* __restrict__ x, const int* __restrict__ sorted,
    const int* __restrict__ offsets, float* __restrict__ out)
{
    const int tid  = blockIdx.x * blockDim.x + threadIdx.x;
    const int node = tid >> 4;          // 16 threads per node
    const int quad = tid & 15;          // which float4 of the 64-feat row
    if (node >= N_NODES) return;

    const int start = offsets[node];
    const int end   = offsets[node + 1];

    float4 acc0 = {0.f, 0.f, 0.f, 0.f};
    float4 acc1 = {0.f, 0.f, 0.f, 0.f};
    const float4* __restrict__ x4 = (const float4*)x;   // row = 16 float4s

    int i = start;
    for (; i + 1 < end; i += 2) {
        int s0 = sorted[i];
        int s1 = sorted[i + 1];
        float4 v0 = x4[(size_t)s0 * 16 + quad];
        float4 v1 = x4[(size_t)s1 * 16 + quad];
        acc0.x += v0.x; acc0.y += v0.y; acc0.z += v0.z; acc0.w += v0.w;
        acc1.x += v1.x; acc1.y += v1.y; acc1.z += v1.z; acc1.w += v1.w;
    }
    if (i < end) {
        float4 v0 = x4[(size_t)sorted[i] * 16 + quad];
        acc0.x += v0.x; acc0.y += v0.y; acc0.z += v0.z; acc0.w += v0.w;
    }

    float4 r;
    r.x = acc0.x + acc1.x; r.y = acc0.y + acc1.y;
    r.z = acc0.z + acc1.z; r.w = acc0.w + acc1.w;
    ((float4*)out)[(size_t)node * 16 + quad] = r;
}

extern "C" void kernel_launch(void* const* d_in, const int* in_sizes, int n_in,
                              void* d_out, int out_size, void* d_ws, size_t ws_size,
                              hipStream_t stream) {
    const float* x = (const float*)d_in[0];
    const int* edge_index = (const int*)d_in[1];    // [2, N_EDGES] flat int32
    const int* src = edge_index;
    const int* dst = edge_index + N_EDGES;
    float* out = (float*)d_out;

    // Workspace (ints): count[N] | offsets[N+1] | rank[E] | sorted[E] | blockSums[391] | blockBase[391]
    int* count     = (int*)d_ws;
    int* offsets   = count + N_NODES;
    int* rank      = offsets + (N_NODES + 1);
    int* sorted    = rank + N_EDGES;
    int* blockSums = sorted + N_EDGES;
    int* blockBase = blockSums + N_SCAN_BLOCKS;

    hipMemsetAsync(count, 0, (size_t)N_NODES * sizeof(int), stream);

    const int eb = 256;
    const int eg = (N_EDGES + eb - 1) / eb;
    histo_rank<<<eg, eb, 0, stream>>>(dst, count, rank);

    scan_local<<<N_SCAN_BLOCKS, SCAN_BLOCK, 0, stream>>>(count, offsets, blockSums);
    scan_blocks<<<1, SCAN2_THREADS, 0, stream>>>(blockSums, blockBase, offsets);
    scan_add_base<<<N_SCAN_BLOCKS, SCAN_BLOCK, 0, stream>>>(offsets, blockBase);

    scatter_src<<<eg, eb, 0, stream>>>(src, dst, rank, offsets, sorted);

    const int gthreads = N_NODES * 16;   // 16 threads per node
    gather_sum4<<<(gthreads + 255) / 256, 256, 0, stream>>>(x, sorted, offsets, out);
}